// Round 10
// baseline (405.940 us; speedup 1.0000x reference)
//
#include <hip/hip_runtime.h>
#include <hip/hip_bf16.h>
#include <math.h>

#define BATCH  2
#define SEQ    2048
#define HID    1024
#define INNER  2048
#define NSTATE 64
#define NTOK   (BATCH * SEQ)
#define TCHUNK 64
#define NCHUNK (SEQ / TCHUNK)
#define NMID   (INNER + 2 * NSTATE)   // 2176

typedef __bf16 bf16x8 __attribute__((ext_vector_type(8)));
typedef float  f32x4  __attribute__((ext_vector_type(4)));

typedef const __attribute__((address_space(1))) char* gas_ptr;
typedef __attribute__((address_space(3))) char*       las_ptr;

__device__ __forceinline__ void gload16(const void* g, void* l) {
  __builtin_amdgcn_global_load_lds((gas_ptr)g, (las_ptr)l, 16, 0, 0);
}

__device__ __forceinline__ unsigned short f2bf(float f) {
  __hip_bfloat16 h = __float2bfloat16(f);
  return __builtin_bit_cast(unsigned short, h);
}
__device__ __forceinline__ float bf2f(unsigned short u) {
  unsigned int x = ((unsigned int)u) << 16;
  return __builtin_bit_cast(float, x);
}
__device__ __forceinline__ void upk(unsigned int u, float& lo, float& hi) {
  lo = bf2f((unsigned short)(u & 0xffffu));
  hi = bf2f((unsigned short)(u >> 16));
}

// ---------------------------------------------------------------- cvt fp32->bf16
__global__ __launch_bounds__(256) void cvt_f32_bf16_kernel(
    const float* __restrict__ in, __hip_bfloat16* __restrict__ out, int n4) {
  int i = blockIdx.x * 256 + threadIdx.x;
  if (i >= n4) return;
  float4 v = ((const float4*)in)[i];
  ushort4 u;
  u.x = f2bf(v.x); u.y = f2bf(v.y); u.z = f2bf(v.z); u.w = f2bf(v.w);
  ((ushort4*)out)[i] = u;
}

// ------------------------------------------------- transpose fp32 [R][C] -> bf16 [C][ostride]
__global__ __launch_bounds__(256) void transpose_cvt_kernel(
    const float* __restrict__ in, __hip_bfloat16* __restrict__ out,
    int R, int C, int ostride) {
  __shared__ float tile[32][33];
  int tx = threadIdx.x & 31, ty = threadIdx.x >> 5;
  int c0 = blockIdx.x * 32, r0 = blockIdx.y * 32;
#pragma unroll
  for (int i = 0; i < 4; ++i)
    tile[ty + 8 * i][tx] = in[(size_t)(r0 + ty + 8 * i) * C + c0 + tx];
  __syncthreads();
#pragma unroll
  for (int i = 0; i < 4; ++i)
    out[(size_t)(c0 + ty + 8 * i) * ostride + r0 + tx] =
        __float2bfloat16(tile[tx][ty + 8 * i]);
}

// ---------------------------------------------------------------- GEMM (unchanged from r8/r9)
template <int EPI>
__global__ __launch_bounds__(256, 4) void gemm_bt_kernel(
    const __hip_bfloat16* __restrict__ A, const __hip_bfloat16* __restrict__ Bt,
    int M, int N, int Klen, int ldk, int gridN, int nwg, int mnwg,
    float* __restrict__ Cout, int ldc,
    __hip_bfloat16* __restrict__ o0, __hip_bfloat16* __restrict__ o1) {
  __shared__ __align__(16) __hip_bfloat16 As[128 * 64];
  __shared__ __align__(16) __hip_bfloat16 Bs[128 * 64];
  const int tid = threadIdx.x;
  const int lane = tid & 63;
  const int w = tid >> 6;
  const int wr = w >> 1, wc = w & 1;

  const int orig = blockIdx.x;
  const int q8 = nwg >> 3, r8 = nwg & 7;
  const int xcd = orig & 7, seq = orig >> 3;
  const int wg = (xcd < r8 ? xcd * (q8 + 1) : r8 * (q8 + 1) + (xcd - r8) * q8) + seq;
  const int kz = wg / mnwg;
  const int wgr = wg - kz * mnwg;
  const int m0 = (wgr / gridN) * 128;
  const int n0 = (wgr % gridN) * 128;

  const __hip_bfloat16* Ab = A + (size_t)kz * Klen;
  const __hip_bfloat16* Bb = Bt + (size_t)kz * Klen;

  f32x4 acc[4][4];
#pragma unroll
  for (int i = 0; i < 4; ++i)
#pragma unroll
    for (int j = 0; j < 4; ++j)
#pragma unroll
      for (int r2 = 0; r2 < 4; ++r2) acc[i][j][r2] = 0.f;

  const int g8row = lane >> 3;
  const int scol = ((lane & 7) ^ g8row) * 8;
  const __hip_bfloat16* Agp = Ab + (size_t)(m0 + w * 32 + g8row) * ldk + scol;
  const __hip_bfloat16* Bgp = Bb + (size_t)(n0 + w * 32 + g8row) * ldk + scol;
  __hip_bfloat16* lA = As + (w * 32) * 64;
  __hip_bfloat16* lB = Bs + (w * 32) * 64;

  const int lrow = lane & 15, lk = lane >> 4;
  const int arow0 = wr * 64 + lrow;
  const int brow0 = wc * 64 + lrow;

  const int nt = Klen >> 6;
  for (int t = 0; t < nt; ++t) {
    __syncthreads();
#pragma unroll
    for (int g = 0; g < 4; ++g) {
      gload16(Agp + (size_t)(g * 8) * ldk + t * 64, lA + (g * 8) * 64);
      gload16(Bgp + (size_t)(g * 8) * ldk + t * 64, lB + (g * 8) * 64);
    }
    __syncthreads();
#pragma unroll
    for (int ss = 0; ss < 2; ++ss) {
      bf16x8 af[4], bv[4];
#pragma unroll
      for (int i = 0; i < 4; ++i) {
        const int ra = arow0 + i * 16;
        af[i] = *(const bf16x8*)(As + ra * 64 + (((ss * 4 + lk) ^ (ra & 7)) * 8));
        const int rb = brow0 + i * 16;
        bv[i] = *(const bf16x8*)(Bs + rb * 64 + (((ss * 4 + lk) ^ (rb & 7)) * 8));
      }
#pragma unroll
      for (int i = 0; i < 4; ++i)
#pragma unroll
        for (int j = 0; j < 4; ++j)
          acc[i][j] = __builtin_amdgcn_mfma_f32_16x16x32_bf16(af[i], bv[j], acc[i][j], 0, 0, 0);
    }
  }

#pragma unroll
  for (int i = 0; i < 4; ++i) {
#pragma unroll
    for (int j = 0; j < 4; ++j) {
#pragma unroll
      for (int r2 = 0; r2 < 4; ++r2) {
        const int row = m0 + wr * 64 + i * 16 + lk * 4 + r2;
        const int col = n0 + wc * 64 + j * 16 + lrow;
        const float v = acc[i][j][r2];
        if constexpr (EPI == 0) {
          Cout[(size_t)kz * M * ldc + (size_t)row * ldc + col] = v;
        } else {
          if (col < INNER) o0[(size_t)row * INNER + col] = __float2bfloat16(v);
          else             o1[(size_t)row * INNER + (col - INNER)] = __float2bfloat16(v);
        }
      }
    }
  }
}

// ---------------------------------------------------------------- mid reduce: P0+P1 -> softplus/dt | Bm | Cm
__global__ __launch_bounds__(256) void reduce_mid_kernel(
    const float* __restrict__ P, const float* __restrict__ bdt,
    float* __restrict__ dtb, float* __restrict__ Bm, float* __restrict__ Cm) {
  const int i = blockIdx.x * 256 + threadIdx.x;
  const int row = i / (NMID / 4);
  const int c4 = i - row * (NMID / 4);
  const int col = c4 * 4;
  const size_t off = (size_t)row * NMID + col;
  float4 a = *(const float4*)&P[off];
  float4 b = *(const float4*)&P[(size_t)NTOK * NMID + off];
  float4 v = make_float4(a.x + b.x, a.y + b.y, a.z + b.z, a.w + b.w);
  if (col < INNER) {
    float4 bb = *(const float4*)&bdt[col];
    float4 d;
    d.x = v.x + bb.x; d.y = v.y + bb.y; d.z = v.z + bb.z; d.w = v.w + bb.w;
    d.x = (d.x > 15.f) ? d.x : log1pf(__expf(d.x));
    d.y = (d.y > 15.f) ? d.y : log1pf(__expf(d.y));
    d.z = (d.z > 15.f) ? d.z : log1pf(__expf(d.z));
    d.w = (d.w > 15.f) ? d.w : log1pf(__expf(d.w));
    *(float4*)&dtb[(size_t)row * INNER + col] = d;
  } else if (col < INNER + NSTATE) {
    *(float4*)&Bm[(size_t)row * NSTATE + (col - INNER)] = v;
  } else {
    *(float4*)&Cm[(size_t)row * NSTATE + (col - INNER - NSTATE)] = v;
  }
}

// ---------------------------------------------------------------- split-K4 reduce (fp32)
__global__ __launch_bounds__(256) void reduce4_kernel(
    const float* __restrict__ P, float* __restrict__ out, int n4) {
  int i = blockIdx.x * 256 + threadIdx.x;
  if (i >= n4) return;
  float4 a = ((const float4*)P)[i];
  float4 b = ((const float4*)P)[i + n4];
  float4 c = ((const float4*)P)[i + 2 * n4];
  float4 d = ((const float4*)P)[i + 3 * n4];
  ((float4*)out)[i] = make_float4((a.x + b.x) + (c.x + d.x), (a.y + b.y) + (c.y + d.y),
                                  (a.z + b.z) + (c.z + d.z), (a.w + b.w) + (c.w + d.w));
}

// ---------------------------------------------------------------- causal depthwise conv + silu
__global__ __launch_bounds__(256) void conv_silu_kernel(
    const __hip_bfloat16* __restrict__ xin, const float* __restrict__ cw,
    const float* __restrict__ cb, __hip_bfloat16* __restrict__ xch) {
  int idx = blockIdx.x * 256 + threadIdx.x;
  int cg = idx & 511;
  int tok = idx >> 9;
  int c = cg * 4;
  int l = tok & (SEQ - 1);
  float wv[4][4];
#pragma unroll
  for (int i = 0; i < 4; ++i) {
    float4 w = *(const float4*)&cw[(c + i) * 4];
    wv[i][0] = w.x; wv[i][1] = w.y; wv[i][2] = w.z; wv[i][3] = w.w;
  }
  float4 bias = *(const float4*)&cb[c];
  float r0 = bias.x, r1 = bias.y, r2 = bias.z, r3 = bias.w;
#pragma unroll
  for (int k = 0; k < 4; ++k) {
    const int d = 3 - k;
    if (l >= d) {
      ushort4 xv = *(const ushort4*)&xin[(size_t)(tok - d) * INNER + c];
      r0 = fmaf(bf2f(xv.x), wv[0][k], r0);
      r1 = fmaf(bf2f(xv.y), wv[1][k], r1);
      r2 = fmaf(bf2f(xv.z), wv[2][k], r2);
      r3 = fmaf(bf2f(xv.w), wv[3][k], r3);
    }
  }
  r0 = r0 / (1.f + __expf(-r0));
  r1 = r1 / (1.f + __expf(-r1));
  r2 = r2 / (1.f + __expf(-r2));
  r3 = r3 / (1.f + __expf(-r3));
  ushort4 u;
  u.x = f2bf(r0); u.y = f2bf(r1); u.z = f2bf(r2); u.w = f2bf(r3);
  *(ushort4*)&xch[(size_t)tok * INNER + c] = u;
}

// ---------------------------------------------------------------- scan phase 1: 4 threads/channel, 16 states each
__global__ __launch_bounds__(256, 8) void scan_state_kernel(
    const float* __restrict__ dtb, const __hip_bfloat16* __restrict__ xch,
    const float* __restrict__ Bm,
    float* __restrict__ S, float* __restrict__ A_chunk) {
  __shared__ __hip_bfloat16 Bsh[TCHUNK][64];
  const int b = blockIdx.z, chunk = blockIdx.y;
  const int tid = threadIdx.x;
  const int h = tid & 3;            // state quarter [h*16, h*16+16)
  const int c = blockIdx.x * 64 + (tid >> 2);
  const int t0 = chunk * TCHUNK;
  for (int i = tid; i < TCHUNK * 16; i += 256) {
    const int row = i >> 4, q = i & 15;
    float4 v = *(const float4*)&Bm[((size_t)(b * SEQ + t0 + row)) * NSTATE + q * 4];
    ushort4 u;
    u.x = f2bf(v.x); u.y = f2bf(v.y); u.z = f2bf(v.z); u.w = f2bf(v.w);
    *(ushort4*)&Bsh[row][q * 4] = u;
  }
  __syncthreads();
  float s[16];
#pragma unroll
  for (int n = 0; n < 16; ++n) s[n] = 0.f;
  float cum = 1.f;
  const size_t base = (size_t)(b * SEQ + t0) * INNER + c;
  for (int t = 0; t < TCHUNK; ++t) {
    const float dtv = dtb[base + (size_t)t * INNER];
    const float at = __expf(-dtv);
    const float xc = bf2f(*(const unsigned short*)&xch[base + (size_t)t * INNER]);
    const float ut = dtv * xc;
    cum *= at;
    const unsigned int* bw = (const unsigned int*)&Bsh[t][h * 16];
#pragma unroll
    for (int q = 0; q < 8; ++q) {
      float lo, hi; upk(bw[q], lo, hi);
      s[2 * q]     = fmaf(at, s[2 * q],     ut * lo);
      s[2 * q + 1] = fmaf(at, s[2 * q + 1], ut * hi);
    }
  }
  const size_t sbase = ((size_t)(b * NCHUNK + chunk) * INNER + c) * NSTATE + h * 16;
#pragma unroll
  for (int q = 0; q < 4; ++q)
    *(float4*)&S[sbase + 4 * q] =
        make_float4(s[4 * q], s[4 * q + 1], s[4 * q + 2], s[4 * q + 3]);
  if (h == 0) A_chunk[(size_t)(b * NCHUNK + chunk) * INNER + c] = cum;
}

// ---------------------------------------------------------------- scan phase 2 (in place, unchanged)
__global__ __launch_bounds__(256) void scan_combine_kernel(
    float* __restrict__ S, const float* __restrict__ A_chunk) {
  const int idx = blockIdx.x * 256 + threadIdx.x;
  const int n = idx & 63;
  const int c = (idx >> 6) & (INNER - 1);
  const int b = idx >> 17;
  float s = 0.f;
  for (int k = 0; k < NCHUNK; ++k) {
    const size_t cs = (size_t)(b * NCHUNK + k) * INNER + c;
    const size_t off = cs * NSTATE + n;
    const float loc = S[off];
    S[off] = s;
    s = fmaf(A_chunk[cs], s, loc);
  }
}

// ---------------------------------------------------------------- scan phase 3: 4 threads/channel + shfl dot-reduce
__global__ __launch_bounds__(256, 6) void scan_out_kernel(
    const float* __restrict__ dtb, const __hip_bfloat16* __restrict__ xch,
    const float* __restrict__ Bm, const float* __restrict__ Cm,
    const float* __restrict__ S_in, const __hip_bfloat16* __restrict__ zbf,
    const float* __restrict__ Dv, __hip_bfloat16* __restrict__ ygated) {
  __shared__ __hip_bfloat16 Bsh[TCHUNK][64];
  __shared__ __hip_bfloat16 Csh[TCHUNK][64];
  const int b = blockIdx.z, chunk = blockIdx.y;
  const int tid = threadIdx.x;
  const int h = tid & 3;
  const int c = blockIdx.x * 64 + (tid >> 2);
  const int t0 = chunk * TCHUNK;
  for (int i = tid; i < TCHUNK * 16; i += 256) {
    const int row = i >> 4, q = i & 15;
    const size_t src = ((size_t)(b * SEQ + t0 + row)) * NSTATE + q * 4;
    float4 v = *(const float4*)&Bm[src];
    ushort4 u;
    u.x = f2bf(v.x); u.y = f2bf(v.y); u.z = f2bf(v.z); u.w = f2bf(v.w);
    *(ushort4*)&Bsh[row][q * 4] = u;
    float4 v2 = *(const float4*)&Cm[src];
    ushort4 u2;
    u2.x = f2bf(v2.x); u2.y = f2bf(v2.y); u2.z = f2bf(v2.z); u2.w = f2bf(v2.w);
    *(ushort4*)&Csh[row][q * 4] = u2;
  }
  __syncthreads();
  float s[16];
  const size_t sbase = ((size_t)(b * NCHUNK + chunk) * INNER + c) * NSTATE + h * 16;
#pragma unroll
  for (int q = 0; q < 4; ++q) {
    const float4 v = *(const float4*)&S_in[sbase + 4 * q];
    s[4 * q] = v.x; s[4 * q + 1] = v.y; s[4 * q + 2] = v.z; s[4 * q + 3] = v.w;
  }
  const float Dc = Dv[c];
  const size_t base = (size_t)(b * SEQ + t0) * INNER + c;
  for (int t = 0; t < TCHUNK; ++t) {
    const float dtv = dtb[base + (size_t)t * INNER];
    const float at = __expf(-dtv);
    const float xc = bf2f(*(const unsigned short*)&xch[base + (size_t)t * INNER]);
    const float ut = dtv * xc;
    const unsigned int* bw = (const unsigned int*)&Bsh[t][h * 16];
    const unsigned int* cw = (const unsigned int*)&Csh[t][h * 16];
    float y = 0.f;
#pragma unroll
    for (int q = 0; q < 8; ++q) {
      float bl, bh, cl2, ch2;
      upk(bw[q], bl, bh);
      upk(cw[q], cl2, ch2);
      s[2 * q]     = fmaf(at, s[2 * q],     ut * bl);
      s[2 * q + 1] = fmaf(at, s[2 * q + 1], ut * bh);
      y = fmaf(s[2 * q], cl2, y);
      y = fmaf(s[2 * q + 1], ch2, y);
    }
    y += __shfl_xor(y, 1);
    y += __shfl_xor(y, 2);
    if (h == 0) {
      const float yt = fmaf(Dc, xc, y);
      const float z = bf2f(*(const unsigned short*)&zbf[base + (size_t)t * INNER]);
      const float g = z / (1.f + __expf(-z));
      *(unsigned short*)&ygated[base + (size_t)t * INNER] = f2bf(yt * g);
    }
  }
}

// ---------------------------------------------------------------- launch
extern "C" void kernel_launch(void* const* d_in, const int* in_sizes, int n_in,
                              void* d_out, int out_size, void* d_ws, size_t ws_size,
                              hipStream_t stream) {
  const float* x      = (const float*)d_in[0];
  const float* W_in   = (const float*)d_in[1];
  const float* conv_w = (const float*)d_in[2];
  const float* conv_b = (const float*)d_in[3];
  const float* W_dt   = (const float*)d_in[4];
  const float* b_dt   = (const float*)d_in[5];
  const float* W_B    = (const float*)d_in[6];
  const float* W_C    = (const float*)d_in[7];
  const float* Dvec   = (const float*)d_in[8];
  const float* W_out  = (const float*)d_in[9];
  float* out = (float*)d_out;

  char* p = (char*)d_ws;
  auto alloc = [&](size_t bytes) {
    char* r = p;
    p += (bytes + 255) & ~(size_t)255;
    return r;
  };
  __hip_bfloat16* xin   = (__hip_bfloat16*)alloc((size_t)NTOK * INNER * 2);
  __hip_bfloat16* zbf   = (__hip_bfloat16*)alloc((size_t)NTOK * INNER * 2);
  char*           scr   = alloc((size_t)NTOK * INNER * 2);
  __hip_bfloat16* WmidT = (__hip_bfloat16*)alloc((size_t)NMID * INNER * 2);
  __hip_bfloat16* WoutT = (__hip_bfloat16*)alloc((size_t)HID * INNER * 2);
  float*          dtb   = (float*)alloc((size_t)NTOK * INNER * 4);
  float*          Bm    = (float*)alloc((size_t)NTOK * NSTATE * 4);
  float*          Cm    = (float*)alloc((size_t)NTOK * NSTATE * 4);
  float*          Pmid  = (float*)alloc((size_t)2 * NTOK * NMID * 4);
  float*          A_chk = (float*)alloc((size_t)BATCH * NCHUNK * INNER * 4);

  __hip_bfloat16* x_bf   = (__hip_bfloat16*)scr;
  __hip_bfloat16* WinT   = (__hip_bfloat16*)(scr + (size_t)NTOK * HID * 2);
  __hip_bfloat16* xch    = (__hip_bfloat16*)scr;
  __hip_bfloat16* ygated = xin;
  float*          S      = Pmid;
  float*          Pout   = Pmid;

  // 1. conversions / transposes
  cvt_f32_bf16_kernel<<<(NTOK * HID / 4 + 255) / 256, 256, 0, stream>>>(x, x_bf, NTOK * HID / 4);
  transpose_cvt_kernel<<<dim3((2 * INNER) / 32, HID / 32), 256, 0, stream>>>(W_in, WinT, HID, 2 * INNER, HID);
  transpose_cvt_kernel<<<dim3(INNER / 32, INNER / 32), 256, 0, stream>>>(W_dt, WmidT, INNER, INNER, INNER);
  transpose_cvt_kernel<<<dim3(NSTATE / 32, INNER / 32), 256, 0, stream>>>(
      W_B, WmidT + (size_t)INNER * INNER, INNER, NSTATE, INNER);
  transpose_cvt_kernel<<<dim3(NSTATE / 32, INNER / 32), 256, 0, stream>>>(
      W_C, WmidT + (size_t)(INNER + NSTATE) * INNER, INNER, NSTATE, INNER);
  transpose_cvt_kernel<<<dim3(HID / 32, INNER / 32), 256, 0, stream>>>(W_out, WoutT, INNER, HID, INNER);

  // 2. xz = x @ W_in -> split bf16 (xin | z)
  {
    const int gridN = (2 * INNER) / 128, nwg = (NTOK / 128) * gridN;
    gemm_bt_kernel<1><<<nwg, 256, 0, stream>>>(
        x_bf, WinT, NTOK, 2 * INNER, HID, HID, gridN, nwg, nwg, nullptr, 0, xin, zbf);
  }

  // 3. conv + silu
  conv_silu_kernel<<<(NTOK * (INNER / 4)) / 256, 256, 0, stream>>>(xin, conv_w, conv_b, xch);

  // 4. mid GEMM split-K x2 + fused reduce/softplus
  {
    const int gridN = NMID / 128;
    const int mnwg = (NTOK / 128) * gridN;
    const int nwg = mnwg * 2;
    gemm_bt_kernel<0><<<nwg, 256, 0, stream>>>(
        xch, WmidT, NTOK, NMID, INNER / 2, INNER, gridN, nwg, mnwg, Pmid, NMID,
        nullptr, nullptr);
    reduce_mid_kernel<<<(NTOK * (NMID / 4)) / 256, 256, 0, stream>>>(Pmid, b_dt, dtb, Bm, Cm);
  }

  // 5. chunked selective scan (4 threads/channel)
  scan_state_kernel<<<dim3(INNER / 64, NCHUNK, BATCH), 256, 0, stream>>>(dtb, xch, Bm, S, A_chk);
  scan_combine_kernel<<<(BATCH * INNER * NSTATE) / 256, 256, 0, stream>>>(S, A_chk);
  scan_out_kernel<<<dim3(INNER / 64, NCHUNK, BATCH), 256, 0, stream>>>(
      dtb, xch, Bm, Cm, S, zbf, Dvec, ygated);

  // 6. out = ygated @ W_out, split-K x4 + reduce
  {
    const int gridN = HID / 128;
    const int mnwg = (NTOK / 128) * gridN;
    const int nwg = mnwg * 4;
    gemm_bt_kernel<0><<<nwg, 256, 0, stream>>>(
        ygated, WoutT, NTOK, HID, INNER / 4, INNER, gridN, nwg, mnwg, Pout, HID,
        nullptr, nullptr);
    const int n4 = NTOK * HID / 4;
    reduce4_kernel<<<(n4 + 255) / 256, 256, 0, stream>>>(Pout, out, n4);
  }
}

// Round 11
// 377.970 us; speedup vs baseline: 1.0740x; 1.0740x over previous
//
#include <hip/hip_runtime.h>
#include <hip/hip_bf16.h>
#include <math.h>

#define BATCH  2
#define SEQ    2048
#define HID    1024
#define INNER  2048
#define NSTATE 64
#define NTOK   (BATCH * SEQ)
#define TCHUNK 64
#define NCHUNK (SEQ / TCHUNK)
#define NMID   (INNER + 2 * NSTATE)   // 2176

typedef __bf16 bf16x8 __attribute__((ext_vector_type(8)));
typedef float  f32x4  __attribute__((ext_vector_type(4)));

typedef const __attribute__((address_space(1))) char* gas_ptr;
typedef __attribute__((address_space(3))) char*       las_ptr;

__device__ __forceinline__ void gload16(const void* g, void* l) {
  __builtin_amdgcn_global_load_lds((gas_ptr)g, (las_ptr)l, 16, 0, 0);
}

__device__ __forceinline__ unsigned short f2bf(float f) {
  __hip_bfloat16 h = __float2bfloat16(f);
  return __builtin_bit_cast(unsigned short, h);
}
__device__ __forceinline__ float bf2f(unsigned short u) {
  unsigned int x = ((unsigned int)u) << 16;
  return __builtin_bit_cast(float, x);
}

// ---------------------------------------------------------------- cvt fp32->bf16
__global__ __launch_bounds__(256) void cvt_f32_bf16_kernel(
    const float* __restrict__ in, __hip_bfloat16* __restrict__ out, int n4) {
  int i = blockIdx.x * 256 + threadIdx.x;
  if (i >= n4) return;
  float4 v = ((const float4*)in)[i];
  ushort4 u;
  u.x = f2bf(v.x); u.y = f2bf(v.y); u.z = f2bf(v.z); u.w = f2bf(v.w);
  ((ushort4*)out)[i] = u;
}

// ------------------------------------------------- transpose fp32 [R][C] -> bf16 [C][ostride]
__global__ __launch_bounds__(256) void transpose_cvt_kernel(
    const float* __restrict__ in, __hip_bfloat16* __restrict__ out,
    int R, int C, int ostride) {
  __shared__ float tile[32][33];
  int tx = threadIdx.x & 31, ty = threadIdx.x >> 5;
  int c0 = blockIdx.x * 32, r0 = blockIdx.y * 32;
#pragma unroll
  for (int i = 0; i < 4; ++i)
    tile[ty + 8 * i][tx] = in[(size_t)(r0 + ty + 8 * i) * C + c0 + tx];
  __syncthreads();
#pragma unroll
  for (int i = 0; i < 4; ++i)
    out[(size_t)(c0 + ty + 8 * i) * ostride + r0 + tx] =
        __float2bfloat16(tile[tx][ty + 8 * i]);
}

// ---------------------------------------------------------------- GEMM (unchanged from r9)
template <int EPI>
__global__ __launch_bounds__(256, 4) void gemm_bt_kernel(
    const __hip_bfloat16* __restrict__ A, const __hip_bfloat16* __restrict__ Bt,
    int M, int N, int Klen, int ldk, int gridN, int nwg, int mnwg,
    float* __restrict__ Cout, int ldc,
    __hip_bfloat16* __restrict__ o0, __hip_bfloat16* __restrict__ o1) {
  __shared__ __align__(16) __hip_bfloat16 As[128 * 64];
  __shared__ __align__(16) __hip_bfloat16 Bs[128 * 64];
  const int tid = threadIdx.x;
  const int lane = tid & 63;
  const int w = tid >> 6;
  const int wr = w >> 1, wc = w & 1;

  const int orig = blockIdx.x;
  const int q8 = nwg >> 3, r8 = nwg & 7;
  const int xcd = orig & 7, seq = orig >> 3;
  const int wg = (xcd < r8 ? xcd * (q8 + 1) : r8 * (q8 + 1) + (xcd - r8) * q8) + seq;
  const int kz = wg / mnwg;
  const int wgr = wg - kz * mnwg;
  const int m0 = (wgr / gridN) * 128;
  const int n0 = (wgr % gridN) * 128;

  const __hip_bfloat16* Ab = A + (size_t)kz * Klen;
  const __hip_bfloat16* Bb = Bt + (size_t)kz * Klen;

  f32x4 acc[4][4];
#pragma unroll
  for (int i = 0; i < 4; ++i)
#pragma unroll
    for (int j = 0; j < 4; ++j)
#pragma unroll
      for (int r2 = 0; r2 < 4; ++r2) acc[i][j][r2] = 0.f;

  const int g8row = lane >> 3;
  const int scol = ((lane & 7) ^ g8row) * 8;
  const __hip_bfloat16* Agp = Ab + (size_t)(m0 + w * 32 + g8row) * ldk + scol;
  const __hip_bfloat16* Bgp = Bb + (size_t)(n0 + w * 32 + g8row) * ldk + scol;
  __hip_bfloat16* lA = As + (w * 32) * 64;
  __hip_bfloat16* lB = Bs + (w * 32) * 64;

  const int lrow = lane & 15, lk = lane >> 4;
  const int arow0 = wr * 64 + lrow;
  const int brow0 = wc * 64 + lrow;

  const int nt = Klen >> 6;
  for (int t = 0; t < nt; ++t) {
    __syncthreads();
#pragma unroll
    for (int g = 0; g < 4; ++g) {
      gload16(Agp + (size_t)(g * 8) * ldk + t * 64, lA + (g * 8) * 64);
      gload16(Bgp + (size_t)(g * 8) * ldk + t * 64, lB + (g * 8) * 64);
    }
    __syncthreads();
#pragma unroll
    for (int ss = 0; ss < 2; ++ss) {
      bf16x8 af[4], bv[4];
#pragma unroll
      for (int i = 0; i < 4; ++i) {
        const int ra = arow0 + i * 16;
        af[i] = *(const bf16x8*)(As + ra * 64 + (((ss * 4 + lk) ^ (ra & 7)) * 8));
        const int rb = brow0 + i * 16;
        bv[i] = *(const bf16x8*)(Bs + rb * 64 + (((ss * 4 + lk) ^ (rb & 7)) * 8));
      }
#pragma unroll
      for (int i = 0; i < 4; ++i)
#pragma unroll
        for (int j = 0; j < 4; ++j)
          acc[i][j] = __builtin_amdgcn_mfma_f32_16x16x32_bf16(af[i], bv[j], acc[i][j], 0, 0, 0);
    }
  }

#pragma unroll
  for (int i = 0; i < 4; ++i) {
#pragma unroll
    for (int j = 0; j < 4; ++j) {
#pragma unroll
      for (int r2 = 0; r2 < 4; ++r2) {
        const int row = m0 + wr * 64 + i * 16 + lk * 4 + r2;
        const int col = n0 + wc * 64 + j * 16 + lrow;
        const float v = acc[i][j][r2];
        if constexpr (EPI == 0) {
          Cout[(size_t)kz * M * ldc + (size_t)row * ldc + col] = v;
        } else {
          if (col < INNER) o0[(size_t)row * INNER + col] = __float2bfloat16(v);
          else             o1[(size_t)row * INNER + (col - INNER)] = __float2bfloat16(v);
        }
      }
    }
  }
}

// ---------------------------------------------------------------- mid reduce: P0+P1 -> softplus/dt | Bm | Cm
__global__ __launch_bounds__(256) void reduce_mid_kernel(
    const float* __restrict__ P, const float* __restrict__ bdt,
    float* __restrict__ dtb, float* __restrict__ Bm, float* __restrict__ Cm) {
  const int i = blockIdx.x * 256 + threadIdx.x;
  const int row = i / (NMID / 4);
  const int c4 = i - row * (NMID / 4);
  const int col = c4 * 4;
  const size_t off = (size_t)row * NMID + col;
  float4 a = *(const float4*)&P[off];
  float4 b = *(const float4*)&P[(size_t)NTOK * NMID + off];
  float4 v = make_float4(a.x + b.x, a.y + b.y, a.z + b.z, a.w + b.w);
  if (col < INNER) {
    float4 bb = *(const float4*)&bdt[col];
    float4 d;
    d.x = v.x + bb.x; d.y = v.y + bb.y; d.z = v.z + bb.z; d.w = v.w + bb.w;
    d.x = (d.x > 15.f) ? d.x : log1pf(__expf(d.x));
    d.y = (d.y > 15.f) ? d.y : log1pf(__expf(d.y));
    d.z = (d.z > 15.f) ? d.z : log1pf(__expf(d.z));
    d.w = (d.w > 15.f) ? d.w : log1pf(__expf(d.w));
    *(float4*)&dtb[(size_t)row * INNER + col] = d;
  } else if (col < INNER + NSTATE) {
    *(float4*)&Bm[(size_t)row * NSTATE + (col - INNER)] = v;
  } else {
    *(float4*)&Cm[(size_t)row * NSTATE + (col - INNER - NSTATE)] = v;
  }
}

// ---------------------------------------------------------------- split-K4 reduce (fp32)
__global__ __launch_bounds__(256) void reduce4_kernel(
    const float* __restrict__ P, float* __restrict__ out, int n4) {
  int i = blockIdx.x * 256 + threadIdx.x;
  if (i >= n4) return;
  float4 a = ((const float4*)P)[i];
  float4 b = ((const float4*)P)[i + n4];
  float4 c = ((const float4*)P)[i + 2 * n4];
  float4 d = ((const float4*)P)[i + 3 * n4];
  ((float4*)out)[i] = make_float4((a.x + b.x) + (c.x + d.x), (a.y + b.y) + (c.y + d.y),
                                  (a.z + b.z) + (c.z + d.z), (a.w + b.w) + (c.w + d.w));
}

// ---------------------------------------------------------------- causal depthwise conv + silu
__global__ __launch_bounds__(256) void conv_silu_kernel(
    const __hip_bfloat16* __restrict__ xin, const float* __restrict__ cw,
    const float* __restrict__ cb, __hip_bfloat16* __restrict__ xch) {
  int idx = blockIdx.x * 256 + threadIdx.x;
  int cg = idx & 511;
  int tok = idx >> 9;
  int c = cg * 4;
  int l = tok & (SEQ - 1);
  float wv[4][4];
#pragma unroll
  for (int i = 0; i < 4; ++i) {
    float4 w = *(const float4*)&cw[(c + i) * 4];
    wv[i][0] = w.x; wv[i][1] = w.y; wv[i][2] = w.z; wv[i][3] = w.w;
  }
  float4 bias = *(const float4*)&cb[c];
  float r0 = bias.x, r1 = bias.y, r2 = bias.z, r3 = bias.w;
#pragma unroll
  for (int k = 0; k < 4; ++k) {
    const int d = 3 - k;
    if (l >= d) {
      ushort4 xv = *(const ushort4*)&xin[(size_t)(tok - d) * INNER + c];
      r0 = fmaf(bf2f(xv.x), wv[0][k], r0);
      r1 = fmaf(bf2f(xv.y), wv[1][k], r1);
      r2 = fmaf(bf2f(xv.z), wv[2][k], r2);
      r3 = fmaf(bf2f(xv.w), wv[3][k], r3);
    }
  }
  r0 = r0 / (1.f + __expf(-r0));
  r1 = r1 / (1.f + __expf(-r1));
  r2 = r2 / (1.f + __expf(-r2));
  r3 = r3 / (1.f + __expf(-r3));
  ushort4 u;
  u.x = f2bf(r0); u.y = f2bf(r1); u.z = f2bf(r2); u.w = f2bf(r3);
  *(ushort4*)&xch[(size_t)tok * INNER + c] = u;
}

// ---------------------------------------------------------------- scan phase 1: 2 threads/channel, 32 states each
__global__ __launch_bounds__(256, 4) void scan_state_kernel(
    const float* __restrict__ dtb, const __hip_bfloat16* __restrict__ xch,
    const float* __restrict__ Bm,
    float* __restrict__ S, float* __restrict__ A_chunk) {
  __shared__ float Bsh[TCHUNK][64];
  const int b = blockIdx.z, chunk = blockIdx.y;
  const int tid = threadIdx.x;
  const int h = tid & 1;              // state half [h*32, h*32+32)
  const int c = blockIdx.x * 128 + (tid >> 1);
  const int t0 = chunk * TCHUNK;
  for (int i = tid; i < TCHUNK * 16; i += 256) {
    const int row = i >> 4, q = i & 15;
    *(float4*)&Bsh[row][q * 4] =
        *(const float4*)&Bm[((size_t)(b * SEQ + t0 + row)) * NSTATE + q * 4];
  }
  __syncthreads();
  float s[32];
#pragma unroll
  for (int n = 0; n < 32; ++n) s[n] = 0.f;
  float p = 1.f;
  const size_t base = (size_t)(b * SEQ + t0) * INNER + c;
  for (int t = 0; t < TCHUNK; ++t) {
    const float dtv = dtb[base + (size_t)t * INNER];
    const float at = __expf(-dtv);
    const float xc = bf2f(*(const unsigned short*)&xch[base + (size_t)t * INNER]);
    const float ut = dtv * xc;
    p *= at;
    const float* brow = &Bsh[t][h * 32];
#pragma unroll
    for (int q = 0; q < 8; ++q) {
      const float4 bv = *(const float4*)&brow[q * 4];
      s[4 * q + 0] = fmaf(at, s[4 * q + 0], ut * bv.x);
      s[4 * q + 1] = fmaf(at, s[4 * q + 1], ut * bv.y);
      s[4 * q + 2] = fmaf(at, s[4 * q + 2], ut * bv.z);
      s[4 * q + 3] = fmaf(at, s[4 * q + 3], ut * bv.w);
    }
  }
  const size_t sbase = ((size_t)(b * NCHUNK + chunk) * INNER + c) * NSTATE + h * 32;
#pragma unroll
  for (int q = 0; q < 8; ++q)
    *(float4*)&S[sbase + 4 * q] =
        make_float4(s[4 * q], s[4 * q + 1], s[4 * q + 2], s[4 * q + 3]);
  if (h == 0) A_chunk[(size_t)(b * NCHUNK + chunk) * INNER + c] = p;
}

// ---------------------------------------------------------------- scan phase 2 (in place, unchanged)
__global__ __launch_bounds__(256) void scan_combine_kernel(
    float* __restrict__ S, const float* __restrict__ A_chunk) {
  const int idx = blockIdx.x * 256 + threadIdx.x;
  const int n = idx & 63;
  const int c = (idx >> 6) & (INNER - 1);
  const int b = idx >> 17;
  float s = 0.f;
  for (int k = 0; k < NCHUNK; ++k) {
    const size_t cs = (size_t)(b * NCHUNK + k) * INNER + c;
    const size_t off = cs * NSTATE + n;
    const float loc = S[off];
    S[off] = s;
    s = fmaf(A_chunk[cs], s, loc);
  }
}

// ---------------------------------------------------------------- scan phase 3: 2 threads/channel + shfl dot-reduce
__global__ __launch_bounds__(256, 4) void scan_out_kernel(
    const float* __restrict__ dtb, const __hip_bfloat16* __restrict__ xch,
    const float* __restrict__ Bm, const float* __restrict__ Cm,
    const float* __restrict__ S_in, const __hip_bfloat16* __restrict__ zbf,
    const float* __restrict__ Dv, __hip_bfloat16* __restrict__ ygated) {
  __shared__ float Bsh[TCHUNK][64];
  __shared__ float Csh[TCHUNK][64];
  const int b = blockIdx.z, chunk = blockIdx.y;
  const int tid = threadIdx.x;
  const int h = tid & 1;
  const int c = blockIdx.x * 128 + (tid >> 1);
  const int t0 = chunk * TCHUNK;
  for (int i = tid; i < TCHUNK * 16; i += 256) {
    const int row = i >> 4, q = i & 15;
    const size_t src = ((size_t)(b * SEQ + t0 + row)) * NSTATE + q * 4;
    *(float4*)&Bsh[row][q * 4] = *(const float4*)&Bm[src];
    *(float4*)&Csh[row][q * 4] = *(const float4*)&Cm[src];
  }
  __syncthreads();
  float s[32];
  const size_t sbase = ((size_t)(b * NCHUNK + chunk) * INNER + c) * NSTATE + h * 32;
#pragma unroll
  for (int q = 0; q < 8; ++q) {
    const float4 v = *(const float4*)&S_in[sbase + 4 * q];
    s[4 * q] = v.x; s[4 * q + 1] = v.y; s[4 * q + 2] = v.z; s[4 * q + 3] = v.w;
  }
  const float Dc = Dv[c];
  const size_t base = (size_t)(b * SEQ + t0) * INNER + c;
  for (int t = 0; t < TCHUNK; ++t) {
    const float dtv = dtb[base + (size_t)t * INNER];
    const float at = __expf(-dtv);
    const float xc = bf2f(*(const unsigned short*)&xch[base + (size_t)t * INNER]);
    const float ut = dtv * xc;
    const float* brow = &Bsh[t][h * 32];
    const float* crow = &Csh[t][h * 32];
    float y0 = 0.f, y1 = 0.f, y2 = 0.f, y3 = 0.f;
#pragma unroll
    for (int q = 0; q < 8; ++q) {
      const float4 bv = *(const float4*)&brow[q * 4];
      const float4 cv = *(const float4*)&crow[q * 4];
      s[4 * q + 0] = fmaf(at, s[4 * q + 0], ut * bv.x);
      s[4 * q + 1] = fmaf(at, s[4 * q + 1], ut * bv.y);
      s[4 * q + 2] = fmaf(at, s[4 * q + 2], ut * bv.z);
      s[4 * q + 3] = fmaf(at, s[4 * q + 3], ut * bv.w);
      y0 = fmaf(s[4 * q + 0], cv.x, y0);
      y1 = fmaf(s[4 * q + 1], cv.y, y1);
      y2 = fmaf(s[4 * q + 2], cv.z, y2);
      y3 = fmaf(s[4 * q + 3], cv.w, y3);
    }
    float y = (y0 + y1) + (y2 + y3);
    y += __shfl_xor(y, 1);
    if (h == 0) {
      const float yt = fmaf(Dc, xc, y);
      const float z = bf2f(*(const unsigned short*)&zbf[base + (size_t)t * INNER]);
      const float g = z / (1.f + __expf(-z));
      *(unsigned short*)&ygated[base + (size_t)t * INNER] = f2bf(yt * g);
    }
  }
}

// ---------------------------------------------------------------- launch
extern "C" void kernel_launch(void* const* d_in, const int* in_sizes, int n_in,
                              void* d_out, int out_size, void* d_ws, size_t ws_size,
                              hipStream_t stream) {
  const float* x      = (const float*)d_in[0];
  const float* W_in   = (const float*)d_in[1];
  const float* conv_w = (const float*)d_in[2];
  const float* conv_b = (const float*)d_in[3];
  const float* W_dt   = (const float*)d_in[4];
  const float* b_dt   = (const float*)d_in[5];
  const float* W_B    = (const float*)d_in[6];
  const float* W_C    = (const float*)d_in[7];
  const float* Dvec   = (const float*)d_in[8];
  const float* W_out  = (const float*)d_in[9];
  float* out = (float*)d_out;

  char* p = (char*)d_ws;
  auto alloc = [&](size_t bytes) {
    char* r = p;
    p += (bytes + 255) & ~(size_t)255;
    return r;
  };
  __hip_bfloat16* xin   = (__hip_bfloat16*)alloc((size_t)NTOK * INNER * 2);
  __hip_bfloat16* zbf   = (__hip_bfloat16*)alloc((size_t)NTOK * INNER * 2);
  char*           scr   = alloc((size_t)NTOK * INNER * 2);
  __hip_bfloat16* WmidT = (__hip_bfloat16*)alloc((size_t)NMID * INNER * 2);
  __hip_bfloat16* WoutT = (__hip_bfloat16*)alloc((size_t)HID * INNER * 2);
  float*          dtb   = (float*)alloc((size_t)NTOK * INNER * 4);
  float*          Bm    = (float*)alloc((size_t)NTOK * NSTATE * 4);
  float*          Cm    = (float*)alloc((size_t)NTOK * NSTATE * 4);
  float*          Pmid  = (float*)alloc((size_t)2 * NTOK * NMID * 4);
  float*          A_chk = (float*)alloc((size_t)BATCH * NCHUNK * INNER * 4);

  __hip_bfloat16* x_bf   = (__hip_bfloat16*)scr;
  __hip_bfloat16* WinT   = (__hip_bfloat16*)(scr + (size_t)NTOK * HID * 2);
  __hip_bfloat16* xch    = (__hip_bfloat16*)scr;
  __hip_bfloat16* ygated = xin;
  float*          S      = Pmid;
  float*          Pout   = Pmid;

  // 1. conversions / transposes
  cvt_f32_bf16_kernel<<<(NTOK * HID / 4 + 255) / 256, 256, 0, stream>>>(x, x_bf, NTOK * HID / 4);
  transpose_cvt_kernel<<<dim3((2 * INNER) / 32, HID / 32), 256, 0, stream>>>(W_in, WinT, HID, 2 * INNER, HID);
  transpose_cvt_kernel<<<dim3(INNER / 32, INNER / 32), 256, 0, stream>>>(W_dt, WmidT, INNER, INNER, INNER);
  transpose_cvt_kernel<<<dim3(NSTATE / 32, INNER / 32), 256, 0, stream>>>(
      W_B, WmidT + (size_t)INNER * INNER, INNER, NSTATE, INNER);
  transpose_cvt_kernel<<<dim3(NSTATE / 32, INNER / 32), 256, 0, stream>>>(
      W_C, WmidT + (size_t)(INNER + NSTATE) * INNER, INNER, NSTATE, INNER);
  transpose_cvt_kernel<<<dim3(HID / 32, INNER / 32), 256, 0, stream>>>(W_out, WoutT, INNER, HID, INNER);

  // 2. xz = x @ W_in -> split bf16 (xin | z)
  {
    const int gridN = (2 * INNER) / 128, nwg = (NTOK / 128) * gridN;
    gemm_bt_kernel<1><<<nwg, 256, 0, stream>>>(
        x_bf, WinT, NTOK, 2 * INNER, HID, HID, gridN, nwg, nwg, nullptr, 0, xin, zbf);
  }

  // 3. conv + silu
  conv_silu_kernel<<<(NTOK * (INNER / 4)) / 256, 256, 0, stream>>>(xin, conv_w, conv_b, xch);

  // 4. mid GEMM split-K x2 + fused reduce/softplus
  {
    const int gridN = NMID / 128;
    const int mnwg = (NTOK / 128) * gridN;
    const int nwg = mnwg * 2;
    gemm_bt_kernel<0><<<nwg, 256, 0, stream>>>(
        xch, WmidT, NTOK, NMID, INNER / 2, INNER, gridN, nwg, mnwg, Pmid, NMID,
        nullptr, nullptr);
    reduce_mid_kernel<<<(NTOK * (NMID / 4)) / 256, 256, 0, stream>>>(Pmid, b_dt, dtb, Bm, Cm);
  }

  // 5. chunked selective scan (2 threads/channel)
  scan_state_kernel<<<dim3(INNER / 128, NCHUNK, BATCH), 256, 0, stream>>>(dtb, xch, Bm, S, A_chk);
  scan_combine_kernel<<<(BATCH * INNER * NSTATE) / 256, 256, 0, stream>>>(S, A_chk);
  scan_out_kernel<<<dim3(INNER / 128, NCHUNK, BATCH), 256, 0, stream>>>(
      dtb, xch, Bm, Cm, S, zbf, Dvec, ygated);

  // 6. out = ygated @ W_out, split-K x4 + reduce
  {
    const int gridN = HID / 128;
    const int mnwg = (NTOK / 128) * gridN;
    const int nwg = mnwg * 4;
    gemm_bt_kernel<0><<<nwg, 256, 0, stream>>>(
        ygated, WoutT, NTOK, HID, INNER / 4, INNER, gridN, nwg, mnwg, Pout, HID,
        nullptr, nullptr);
    const int n4 = NTOK * HID / 4;
    reduce4_kernel<<<(n4 + 255) / 256, 256, 0, stream>>>(Pout, out, n4);
  }
}